// Round 5
// baseline (179.849 us; speedup 1.0000x reference)
//
#include <hip/hip_runtime.h>

// ---------------------------------------------------------------------------
// TripletContrastiveLoss on MI355X (gfx950)  — Round 17
// Evidence through R16: tile_mindist pinned at ~92 µs across FETCH 103->28MB
// (XCD mapping), occupancy cuts (R13/R14 regress), LDS removal (R15 regress).
// Diagnosis: ~600 cyc work vs ~1700 cyc wall per block-step; barrier lockstep
// leaves only ~4 independent pipelines/CU to hide the gap. R15 showed raw
// independence without LDS staging trades into TA-transaction-bound.
// R17: maximum independence at UNCHANGED per-step efficiency:
//   * 64x64 tiles, 1-WAVE (64-thread) blocks, 16 KiB LDS each
//     -> 10 fully-independent resident blocks/CU (160 KiB), 2560 blocks,
//        ZERO barriers (wave-private LDS, per-wave counted s_waitcnt)
//   * stage k+2 after lgkmcnt(0) (frees the buffer being read);
//     consume k+1 after vmcnt(8) — k+2's copies stay in flight (per-wave T4,
//     zero occupancy cost). In-order vmcnt retirement makes counts exact.
//   * both-sides LDS swizzle, key=(row>>1)&3 involution: exactly 2 lanes per
//     bank-slot on ds_read_b128 (free) vs 8-way unswizzled.
//   * per-XCD rectangle tile mapping retained (R16's FETCH win).
// Kernels 0/1/3 + launcher: R16-validated, unchanged.
// ---------------------------------------------------------------------------

#define B_ROWS 8192
#define DIM    1024

typedef __bf16 bf16x8 __attribute__((ext_vector_type(8)));
typedef float  f32x4  __attribute__((ext_vector_type(4)));

__device__ __forceinline__ unsigned short f2bf_rne(float x) {
    unsigned u = __float_as_uint(x);
    unsigned r = (u + 0x7FFFu + ((u >> 16) & 1u)) >> 16;
    return (unsigned short)r;
}
__device__ __forceinline__ float bf2f(unsigned short h) {
    return __uint_as_float(((unsigned)h) << 16);
}

// Async global->LDS, 16 B per lane. LDS dest is wave-uniform base; HW places
// lane i at base + 16*i (1 KiB = 16 rows x 64 B chunk).
__device__ __forceinline__ void async_copy16(const void* g, void* l) {
    __builtin_amdgcn_global_load_lds(
        (const __attribute__((address_space(1))) unsigned int*)g,
        (__attribute__((address_space(3))) unsigned int*)l,
        16, 0, 0);
}

// ---------------------------------------------------------------------------
// Kernel 0: slot assignment + accum/ticket init.  (R16-validated)
// ---------------------------------------------------------------------------
__global__ __launch_bounds__(256) void compute_slots(
    const int* __restrict__ dom, int* __restrict__ slotOf,
    unsigned* __restrict__ cnt, float* __restrict__ accum)
{
    __shared__ int cnts[256];
    __shared__ int base[257];
    const int t = threadIdx.x;

    if (t == 0) {
        cnt[1] = 0u;
        accum[0] = 0.0f;
        accum[1] = 0.0f;
    }

    unsigned mask = 0u; int c = 0;
    #pragma unroll
    for (int i = 0; i < 32; ++i) {
        const int isA = (dom[t + 256 * i] == 0) ? 1 : 0;
        mask |= ((unsigned)isA) << i;
        c += isA;
    }
    cnts[t] = c;
    __syncthreads();
    if (t < 64) {
        const int c0 = cnts[4 * t + 0], c1 = cnts[4 * t + 1];
        const int c2 = cnts[4 * t + 2], c3 = cnts[4 * t + 3];
        const int s4 = c0 + c1 + c2 + c3;
        int sc = s4;
        #pragma unroll
        for (int d = 1; d < 64; d <<= 1) {
            const int o = __shfl_up(sc, d);
            if (t >= d) sc += o;
        }
        const int b = sc - s4;
        base[4 * t + 0] = b;
        base[4 * t + 1] = b + c0;
        base[4 * t + 2] = b + c0 + c1;
        base[4 * t + 3] = b + c0 + c1 + c2;
        if (t == 63) { base[256] = sc; cnt[0] = (unsigned)sc; }
    }
    __syncthreads();
    const int nA = base[256];
    int aB = base[t];
    int fB = nA + t * 32 - base[t];
    #pragma unroll
    for (int i = 0; i < 32; ++i) {
        const int isA = (mask >> i) & 1;
        slotOf[t + 256 * i] = isA ? aB : fB;
        aB += isA;
        fB += 1 - isA;
    }
}

// ---------------------------------------------------------------------------
// Kernel 1: L2-normalize -> bf16, scatter to slot; re-init posmin/negmin
// in-place after consuming the overlaid slotOf.  (R16-validated)
// ---------------------------------------------------------------------------
__global__ __launch_bounds__(256) void normalize_rows(
    const float* __restrict__ feat, const int* __restrict__ labels,
    int* slotOf /* aliases posmin */, unsigned* __restrict__ negmin,
    unsigned short* __restrict__ G, int* __restrict__ labG,
    float* __restrict__ sqG)
{
    const int wv = threadIdx.x >> 6, lane = threadIdx.x & 63;
    const int row = blockIdx.x * 4 + wv;

    const float4* src = (const float4*)(feat + (size_t)row * DIM);
    float4 v[4];
    float ss = 0.0f;
    #pragma unroll
    for (int j = 0; j < 4; ++j) {
        v[j] = src[j * 64 + lane];
        ss += v[j].x * v[j].x + v[j].y * v[j].y + v[j].z * v[j].z + v[j].w * v[j].w;
    }
    #pragma unroll
    for (int s = 32; s > 0; s >>= 1) ss += __shfl_xor(ss, s);
    const float inv = 1.0f / fmaxf(sqrtf(ss), 1e-12f);

    const int slot = slotOf[row];
    if (lane == 0) {
        ((unsigned*)slotOf)[row] = 0xFFFFFFFFu;   // posmin[row] = +inf bits
        negmin[row] = 0xFFFFFFFFu;
    }
    unsigned short ub[16];
    float ss2 = 0.0f;
    #pragma unroll
    for (int j = 0; j < 4; ++j) {
        const float f0 = v[j].x * inv, f1 = v[j].y * inv,
                    f2 = v[j].z * inv, f3 = v[j].w * inv;
        ub[j * 4 + 0] = f2bf_rne(f0); ub[j * 4 + 1] = f2bf_rne(f1);
        ub[j * 4 + 2] = f2bf_rne(f2); ub[j * 4 + 3] = f2bf_rne(f3);
        #pragma unroll
        for (int q = 0; q < 4; ++q) {
            const float fr = bf2f(ub[j * 4 + q]);
            ss2 += fr * fr;
        }
    }
    #pragma unroll
    for (int s = 32; s > 0; s >>= 1) ss2 += __shfl_xor(ss2, s);
    if (lane == 0) {
        sqG[slot]  = ss2;
        labG[slot] = labels[row];
    }
    ushort4* dst = (ushort4*)(G + (size_t)slot * DIM);
    #pragma unroll
    for (int j = 0; j < 4; ++j) {
        ushort4 pk;
        pk.x = ub[j * 4 + 0]; pk.y = ub[j * 4 + 1];
        pk.z = ub[j * 4 + 2]; pk.w = ub[j * 4 + 3];
        dst[j * 64 + lane] = pk;
    }
}

// ---------------------------------------------------------------------------
// Kernel 2: 64x64 tiles, ONE WAVE per block (64 thr), 4x4 of 16x16x32 bf16
// MFMA, K=1024 in 32 steps of BK=32. 16 KiB LDS: [buf0/1][A/F][64 rows x
// 32 shorts]. No barriers. Per step s:
//   vmcnt(8)              -> buf[s&1] resident (s+1's 8 copies in flight)
//   ds_read a[4], b[4]    -> swizzled chunks
//   lgkmcnt(0)            -> reads home; buf[s&1] may now be overwritten
//   stage s+2 -> buf[s&1] (8 async copies; guarded s<30)
//   16 MFMA
// Swizzle: LDS phys 16B-chunk p of local row r holds global chunk p ^ key(r),
// key(r) = (r>>1)&3. Write side: source col = ((lane&3) ^ ((srow>>1)&3))*16;
// read side: phys chunk = quad ^ ((l15>>1)&3). Exactly 2 lanes/bank-slot.
// Epilogue identical to validated code modulo 64-row tile indexing.
// ---------------------------------------------------------------------------
__global__ __launch_bounds__(64) void tile_mindist(
    const unsigned short* __restrict__ G, const int* __restrict__ labG,
    const float* __restrict__ sqG, const unsigned* __restrict__ cnt,
    unsigned* __restrict__ posmin, unsigned* __restrict__ negmin)
{
    const int nA = (int)cnt[0];
    const int nF = B_ROWS - nA;
    const int nTA = (nA + 63) >> 6;
    const int nTF = (nF + 63) >> 6;

    // [buf][A=0/F=1][64 rows x 32 shorts] = 16,384 B -> 10 blocks/CU
    __shared__ __align__(16) unsigned short S[2][2][64 * 32];

    const int lane = threadIdx.x;               // single wave
    const int l15 = lane & 15, quad = lane >> 4;

    // Staging: chunk c = rows [16c,16c+16); lane -> row 16c+(lane>>2),
    // phys 16B col (lane&3); SOURCE col = (lane&3) ^ ((srow>>1)&3).
    const int srow  = lane >> 2;
    const int scs16 = (((lane & 3) ^ ((srow >> 1) & 3)) << 4);

    // Read: frag row fm*16+l15 -> key=(l15>>1)&3; phys chunk = quad ^ key.
    const int ch8 = ((quad ^ ((l15 >> 1) & 3)) << 3);   // shorts

    const char* Gb = (const char*)G;

    // ---- per-XCD rectangle mapping (R16-validated algebra) ----
    const int xcd = blockIdx.x & 7;
    const int bx  = xcd & 1;                    // tx band (2)
    const int by  = xcd >> 1;                   // ty band (4)
    const int qa = nTA >> 1, ra = nTA & 1;
    const int sa = qa + ((bx < ra) ? 1 : 0);
    const int xa = bx * qa + ((bx < ra) ? bx : ra);
    const int qf = nTF >> 2, rf = nTF & 3;
    const int sf = qf + ((by < rf) ? 1 : 0);
    const int ya = by * qf + ((by < rf) ? by : rf);
    const int localN = sa * sf;
    const int j0 = blockIdx.x >> 3;             // 0..319
    const int jstride = (int)(gridDim.x >> 3);  // 320

    for (int j = j0; j < localN; j += jstride) {
        const int tx = xa + j / sf;             // slow: A-panel
        const int ty = ya + j % sf;             // fast: sweep F-band
        const int rowA0 = tx * 64;
        const int rowF0 = nA + ty * 64;

        // Per-chunk global bases. A rows < 8192 always (nTA*64 <= 8192);
        // F rows clamped (junk masked in epilogue).
        const char* ga[4]; const char* gf[4];
        #pragma unroll
        for (int c = 0; c < 4; ++c) {
            const int rA = rowA0 + 16 * c + srow;
            int rF = rowF0 + 16 * c + srow;
            if (rF > B_ROWS - 1) rF = B_ROWS - 1;
            ga[c] = Gb + (size_t)rA * (DIM * 2) + scs16;
            gf[c] = Gb + (size_t)rF * (DIM * 2) + scs16;
        }

        f32x4 acc[4][4] = {};

        // Prologue: stage step0 -> buf0 (8 copies FIRST), step1 -> buf1.
        #pragma unroll
        for (int c = 0; c < 4; ++c) async_copy16(ga[c], &S[0][0][c * 512]);
        #pragma unroll
        for (int c = 0; c < 4; ++c) async_copy16(gf[c], &S[0][1][c * 512]);
        #pragma unroll
        for (int c = 0; c < 4; ++c) async_copy16(ga[c] + 64, &S[1][0][c * 512]);
        #pragma unroll
        for (int c = 0; c < 4; ++c) async_copy16(gf[c] + 64, &S[1][1][c * 512]);

        #pragma unroll 4
        for (int step = 0; step < 32; ++step) {
            // buf[step&1] resident; next buffer's 8 copies stay in flight.
            // In-order vmcnt retirement also drains any older epilogue ops.
            if (step < 31) { asm volatile("s_waitcnt vmcnt(8)" ::: "memory"); }
            else           { asm volatile("s_waitcnt vmcnt(0)" ::: "memory"); }

            const int cur = step & 1;
            const unsigned short* pa = &S[cur][0][ch8];
            const unsigned short* pf = &S[cur][1][ch8];
            bf16x8 a[4], b[4];
            #pragma unroll
            for (int fm = 0; fm < 4; ++fm)
                a[fm] = *(const bf16x8*)(pa + (fm * 16 + l15) * 32);
            #pragma unroll
            for (int fn = 0; fn < 4; ++fn)
                b[fn] = *(const bf16x8*)(pf + (fn * 16 + l15) * 32);

            // Reads home -> buf[cur] is free to overwrite with step+2.
            asm volatile("s_waitcnt lgkmcnt(0)" ::: "memory");
            __builtin_amdgcn_sched_barrier(0);
            if (step < 30) {
                const int off = (step + 2) * 64;   // 64 B of K per step
                #pragma unroll
                for (int c = 0; c < 4; ++c)
                    async_copy16(ga[c] + off, &S[cur][0][c * 512]);
                #pragma unroll
                for (int c = 0; c < 4; ++c)
                    async_copy16(gf[c] + off, &S[cur][1][c * 512]);
            }

            #pragma unroll
            for (int fm = 0; fm < 4; ++fm)
                #pragma unroll
                for (int fn = 0; fn < 4; ++fn)
                    acc[fm][fn] = __builtin_amdgcn_mfma_f32_16x16x32_bf16(
                        a[fm], b[fn], acc[fm][fn], 0, 0, 0);
        }

        // Epilogue. C/D layout: col = lane&15 (field), row = quad*4+reg.
        const float INFV = __uint_as_float(0x7f800000u);
        float sqf[4]; int lf_[4]; bool vf[4];
        #pragma unroll
        for (int fn = 0; fn < 4; ++fn) {
            const int rf2 = rowF0 + fn * 16 + l15;
            vf[fn] = rf2 < B_ROWS;
            const int rc = vf[fn] ? rf2 : (B_ROWS - 1);
            sqf[fn] = sqG[rc];
            lf_[fn] = labG[rc];
        }
        #pragma unroll
        for (int fm = 0; fm < 4; ++fm) {
            #pragma unroll
            for (int r = 0; r < 4; ++r) {
                const int ra2 = rowA0 + fm * 16 + quad * 4 + r;
                const bool va = ra2 < nA;
                const int rac = va ? ra2 : 0;
                const float sqa = sqG[rac];
                const int la_ = labG[rac];
                float pmin = INFV, nmin = INFV;
                #pragma unroll
                for (int fn = 0; fn < 4; ++fn) {
                    const float dd = fmaxf(sqa + sqf[fn] - 2.0f * acc[fm][fn][r], 0.0f);
                    if (vf[fn]) {
                        if (la_ == lf_[fn]) pmin = fminf(pmin, dd);
                        else                nmin = fminf(nmin, dd);
                    }
                }
                #pragma unroll
                for (int s = 1; s < 16; s <<= 1) {
                    pmin = fminf(pmin, __shfl_xor(pmin, s));
                    nmin = fminf(nmin, __shfl_xor(nmin, s));
                }
                if (l15 == 0 && va) {
                    if (pmin < INFV) atomicMin(&posmin[ra2], __float_as_uint(pmin));
                    if (nmin < INFV) atomicMin(&negmin[ra2], __float_as_uint(nmin));
                }
            }
        }
        // No barrier between tiles: LDS is wave-private; the next prologue's
        // copies are ordered behind this tile's reads by program order +
        // in-order vmcnt/lgkm retirement.
    }
}

// ---------------------------------------------------------------------------
// Kernel 3: hinge + sum/count with fused finalize via device-scope ticket.
// (R16-validated)
// ---------------------------------------------------------------------------
__global__ __launch_bounds__(256) void reduce_loss(
    const unsigned* __restrict__ posmin, const unsigned* __restrict__ negmin,
    float* __restrict__ accum, unsigned* __restrict__ cnt,
    float* __restrict__ out)
{
    const int i = blockIdx.x * 256 + threadIdx.x;
    const unsigned up = posmin[i], un = negmin[i];
    float tl = 0.0f, c = 0.0f;
    if (up != 0xFFFFFFFFu && un != 0xFFFFFFFFu) {
        const float pd = sqrtf(__uint_as_float(up));
        const float nd = sqrtf(__uint_as_float(un));
        tl = fmaxf(pd - nd + 0.3f, 0.0f);
        c = 1.0f;
    }
    #pragma unroll
    for (int s = 32; s > 0; s >>= 1) {
        tl += __shfl_down(tl, s);
        c  += __shfl_down(c, s);
    }
    __shared__ float sb[8];
    const int lane = threadIdx.x & 63, w = threadIdx.x >> 6;
    if (lane == 0) { sb[w] = tl; sb[4 + w] = c; }
    __syncthreads();
    if (threadIdx.x == 0) {
        atomicAdd(&accum[0], sb[0] + sb[1] + sb[2] + sb[3]);
        atomicAdd(&accum[1], sb[4] + sb[5] + sb[6] + sb[7]);
        __threadfence();
        const unsigned ticket = atomicAdd(&cnt[1], 1u);
        if (ticket == 31u) {               // last of the 32 blocks
            __threadfence();
            const float s2 = atomicAdd(&accum[0], 0.0f);
            const float c2 = atomicAdd(&accum[1], 0.0f);
            out[0] = (c2 > 0.0f) ? s2 / fmaxf(c2, 1.0f) : 0.0f;
        }
    }
}

// ---------------------------------------------------------------------------
extern "C" void kernel_launch(void* const* d_in, const int* in_sizes, int n_in,
                              void* d_out, int out_size, void* d_ws, size_t ws_size,
                              hipStream_t stream) {
    const float* feat  = (const float*)d_in[0];
    const int* labels  = (const int*)d_in[1];
    const int* dom     = (const int*)d_in[2];
    float* out = (float*)d_out;

    char* ws = (char*)d_ws;
    unsigned short* G   = (unsigned short*)(ws);                 // 16,777,216
    int*      labG      = (int*)(ws + 16777216);                 //     32,768
    float*    sqG       = (float*)(ws + 16809984);               //     32,768
    unsigned* posmin    = (unsigned*)(ws + 16842752);            //     32,768
    unsigned* negmin    = (unsigned*)(ws + 16875520);            //     32,768
    unsigned* cnt       = (unsigned*)(ws + 16908288);            //  8 (nA, ticket)
    float*    accum     = (float*)(ws + 16908296);               //  8 (sum, count)
    // slotOf OVERLAYS posmin: written by compute_slots, consumed and then
    // re-initialized to 0xFF in-place by normalize_rows (same-address order).
    int*      slotOf    = (int*)(ws + 16842752);

    compute_slots<<<1, 256, 0, stream>>>(dom, slotOf, cnt, accum);
    normalize_rows<<<B_ROWS / 4, 256, 0, stream>>>(feat, labels, slotOf,
                                                   negmin, G, labG, sqG);

    // 2560 one-wave blocks = 10 per CU (LDS-limited), all resident in one
    // round; per-XCD rectangle mapping inside the kernel.
    tile_mindist<<<2560, 64, 0, stream>>>(G, labG, sqG, cnt, posmin, negmin);

    reduce_loss<<<B_ROWS / 256, 256, 0, stream>>>(posmin, negmin, accum, cnt, out);
}

// Round 6
// 165.156 us; speedup vs baseline: 1.0890x; 1.0890x over previous
//
#include <hip/hip_runtime.h>

// ---------------------------------------------------------------------------
// TripletContrastiveLoss on MI355X (gfx950)  — Round 18
// Evidence R12-R17: latency-bound; waves/CU capped at 16 by VGPR quantization;
// FETCH, bank conflicts, occupancy-depth, LDS-removal all exonerated. The
// un-tested cost: staging TRANSACTION count — column-slice staging fragments
// each 1KB global_load_lds into 16x64B txns (1024 txns/CU/step through one
// TA pipe, serialized ahead of every barrier drain).
// R18 single lever: K-chunk-blocked G layout so staged panels are contiguous:
//   G2[panel=slot>>7][kc 0..31][slot&127][64B]  (64 panels x 256KB = 16MB)
//   * A slots ascend from 0, F slots DESCEND from 8191 -> both tile families
//     always panel-aligned, zero padding, exact 16MB footprint.
//   * staging copy = contiguous 1KB = 8 dense 128B txns (2x fewer, dense).
//   * LDS image identical to R16; F reads use reversed row algebra
//     (u = 127-x, per-lane data unchanged); epilogue F stats at 8191-l.
// K-loop / barriers / grid / XCD mapping: byte-identical to 92us R16.
// ---------------------------------------------------------------------------

#define B_ROWS 8192
#define DIM    1024

typedef __bf16 bf16x8 __attribute__((ext_vector_type(8)));
typedef float  f32x4  __attribute__((ext_vector_type(4)));

__device__ __forceinline__ unsigned short f2bf_rne(float x) {
    unsigned u = __float_as_uint(x);
    unsigned r = (u + 0x7FFFu + ((u >> 16) & 1u)) >> 16;
    return (unsigned short)r;
}
__device__ __forceinline__ float bf2f(unsigned short h) {
    return __uint_as_float(((unsigned)h) << 16);
}

// Async global->LDS, 16 B per lane. LDS dest is wave-uniform base; HW places
// lane i at base + 16*i. With a CONTIGUOUS 1 KiB source, the LDS image is
// 16 rows x 64 B row-major — identical to the consume-side layout.
__device__ __forceinline__ void async_copy16(const void* g, void* l) {
    __builtin_amdgcn_global_load_lds(
        (const __attribute__((address_space(1))) unsigned int*)g,
        (__attribute__((address_space(3))) unsigned int*)l,
        16, 0, 0);
}

// ---------------------------------------------------------------------------
// Kernel 0: slot assignment + accum/ticket init. A rows -> slots ascending
// from 0; F rows -> slots DESCENDING from 8191 (panel-aligned F tiles for
// any nA). Any bijection is valid; downstream agrees on the mapping.
// ---------------------------------------------------------------------------
__global__ __launch_bounds__(256) void compute_slots(
    const int* __restrict__ dom, int* __restrict__ slotOf,
    unsigned* __restrict__ cnt, float* __restrict__ accum)
{
    __shared__ int cnts[256];
    __shared__ int base[257];
    const int t = threadIdx.x;

    if (t == 0) {
        cnt[1] = 0u;
        accum[0] = 0.0f;
        accum[1] = 0.0f;
    }

    unsigned mask = 0u; int c = 0;
    #pragma unroll
    for (int i = 0; i < 32; ++i) {
        const int isA = (dom[t + 256 * i] == 0) ? 1 : 0;
        mask |= ((unsigned)isA) << i;
        c += isA;
    }
    cnts[t] = c;
    __syncthreads();
    if (t < 64) {
        const int c0 = cnts[4 * t + 0], c1 = cnts[4 * t + 1];
        const int c2 = cnts[4 * t + 2], c3 = cnts[4 * t + 3];
        const int s4 = c0 + c1 + c2 + c3;
        int sc = s4;
        #pragma unroll
        for (int d = 1; d < 64; d <<= 1) {
            const int o = __shfl_up(sc, d);
            if (t >= d) sc += o;
        }
        const int b = sc - s4;
        base[4 * t + 0] = b;
        base[4 * t + 1] = b + c0;
        base[4 * t + 2] = b + c0 + c1;
        base[4 * t + 3] = b + c0 + c1 + c2;
        if (t == 63) { base[256] = sc; cnt[0] = (unsigned)sc; }
    }
    __syncthreads();
    int aB = base[t];                 // A slots before this thread
    int fI = t * 32 - base[t];        // F rows before this thread (enum order)
    #pragma unroll
    for (int i = 0; i < 32; ++i) {
        const int isA = (mask >> i) & 1;
        slotOf[t + 256 * i] = isA ? aB : (8191 - fI);
        aB += isA;
        fI += 1 - isA;
    }
}

// ---------------------------------------------------------------------------
// Kernel 1: L2-normalize -> bf16, scatter into K-chunk-BLOCKED G2:
//   byte addr = (slot>>7)*262144 + kc*8192 + (slot&127)*64 + inner
// Per (j,lane): 4 elems e0=j*256+lane*4 -> kc=j*8+(lane>>3), inner=(lane&7)*8.
// sqG/labG stay slot-indexed. posmin/negmin re-init in place (overlay) after
// consuming slotOf.  (R16-validated skeleton)
// ---------------------------------------------------------------------------
__global__ __launch_bounds__(256) void normalize_rows(
    const float* __restrict__ feat, const int* __restrict__ labels,
    int* slotOf /* aliases posmin */, unsigned* __restrict__ negmin,
    unsigned short* __restrict__ G, int* __restrict__ labG,
    float* __restrict__ sqG)
{
    const int wv = threadIdx.x >> 6, lane = threadIdx.x & 63;
    const int row = blockIdx.x * 4 + wv;

    const float4* src = (const float4*)(feat + (size_t)row * DIM);
    float4 v[4];
    float ss = 0.0f;
    #pragma unroll
    for (int j = 0; j < 4; ++j) {
        v[j] = src[j * 64 + lane];
        ss += v[j].x * v[j].x + v[j].y * v[j].y + v[j].z * v[j].z + v[j].w * v[j].w;
    }
    #pragma unroll
    for (int s = 32; s > 0; s >>= 1) ss += __shfl_xor(ss, s);
    const float inv = 1.0f / fmaxf(sqrtf(ss), 1e-12f);

    const int slot = slotOf[row];
    if (lane == 0) {
        ((unsigned*)slotOf)[row] = 0xFFFFFFFFu;   // posmin[row] = +inf bits
        negmin[row] = 0xFFFFFFFFu;
    }
    unsigned short ub[16];
    float ss2 = 0.0f;
    #pragma unroll
    for (int j = 0; j < 4; ++j) {
        const float f0 = v[j].x * inv, f1 = v[j].y * inv,
                    f2 = v[j].z * inv, f3 = v[j].w * inv;
        ub[j * 4 + 0] = f2bf_rne(f0); ub[j * 4 + 1] = f2bf_rne(f1);
        ub[j * 4 + 2] = f2bf_rne(f2); ub[j * 4 + 3] = f2bf_rne(f3);
        #pragma unroll
        for (int q = 0; q < 4; ++q) {
            const float fr = bf2f(ub[j * 4 + q]);
            ss2 += fr * fr;
        }
    }
    #pragma unroll
    for (int s = 32; s > 0; s >>= 1) ss2 += __shfl_xor(ss2, s);
    if (lane == 0) {
        sqG[slot]  = ss2;
        labG[slot] = labels[row];
    }
    // Blocked scatter: base of this slot's panel row.
    char* Gb = (char*)G;
    char* rowBase = Gb + (size_t)(slot >> 7) * 262144 + (size_t)(slot & 127) * 64
                       + (lane & 7) * 8;
    const int kc0 = lane >> 3;                 // 0..7
    #pragma unroll
    for (int j = 0; j < 4; ++j) {
        ushort4 pk;
        pk.x = ub[j * 4 + 0]; pk.y = ub[j * 4 + 1];
        pk.z = ub[j * 4 + 2]; pk.w = ub[j * 4 + 3];
        *(ushort4*)(rowBase + (size_t)(j * 8 + kc0) * 8192) = pk;
    }
}

// ---------------------------------------------------------------------------
// Kernel 2: persistent 128x128 tiles, 4 waves (each 64x64 via 4x4 of
// 16x16x32 bf16 MFMA), K=1024 in 32 steps of BK=32. Structure = 92us R16.
// Staging now reads CONTIGUOUS 1 KiB per copy from the blocked layout:
//   A panel tx:      src = G2 + tx*262144      + step*8192 + c*1024 + lane*16
//   F panel (63-ty): src = G2 + (63-ty)*262144 + step*8192 + c*1024 + lane*16
// LDS row u holds: A local row u; F local row (127-u) [descending slots].
// F fragment reads use u = 127-x (each lane still holds its own row's data).
// Epilogue F stats at slot = 8191 - local. XCD rectangle mapping retained.
// ---------------------------------------------------------------------------
__global__ __launch_bounds__(256) void tile_mindist(
    const unsigned short* __restrict__ G, const int* __restrict__ labG,
    const float* __restrict__ sqG, const unsigned* __restrict__ cnt,
    unsigned* __restrict__ posmin, unsigned* __restrict__ negmin)
{
    const int nA = (int)cnt[0];
    const int nF = B_ROWS - nA;
    const int nTA = (nA + 127) >> 7;
    const int nTF = (nF + 127) >> 7;

    // [buf][A=0/F=1][128 rows x 32 shorts (64 B, unpadded)] = 32,768 B
    __shared__ __align__(16) unsigned short S[2][2][128 * 32];

    const int t = threadIdx.x;
    const int lane = t & 63, w = t >> 6;
    const int wm = w >> 1, wn = w & 1;          // wave sub-tile coords (x64)
    const int l15 = lane & 15, quad = lane >> 4;

    // Staging: wave w owns chunks 2w, 2w+1 (16 rows x 64 B each, contiguous).
    const int ch0 = 2 * w;

    // Fragment read offsets (shorts), row stride 32 shorts.
    const int rdA  = (wm * 64 + l15) * 32 + quad * 8;
    const int rdF0 = ((1 - wn) * 64 + 15 - l15) * 32 + quad * 8;  // + (3-fn)*512

    const char* Gb = (const char*)G;

    // ---- per-XCD rectangle mapping (R16-validated algebra) ----
    const int xcd = blockIdx.x & 7;
    const int bx  = xcd & 1;                    // tx band (2)
    const int by  = xcd >> 1;                   // ty band (4)
    const int qa = nTA >> 1, ra = nTA & 1;
    const int sa = qa + ((bx < ra) ? 1 : 0);
    const int xa = bx * qa + ((bx < ra) ? bx : ra);
    const int qf = nTF >> 2, rf = nTF & 3;
    const int sf = qf + ((by < rf) ? 1 : 0);
    const int ya = by * qf + ((by < rf) ? by : rf);
    const int localN = sa * sf;
    const int j0 = blockIdx.x >> 3;             // 0..131
    const int jstride = (int)(gridDim.x >> 3);  // 132

    for (int j = j0; j < localN; j += jstride) {
        const int tx = xa + j / sf;             // slow: A-panel
        const int ty = ya + j % sf;             // fast: sweep F-band
        const int rowA0  = tx * 128;            // A slot base
        const int rowFl0 = ty * 128;            // F LOCAL base

        // Contiguous panel bases (blocked layout).
        const char* baseA = Gb + (size_t)tx * 262144 + (size_t)(ch0 * 1024) + lane * 16;
        const char* baseF = Gb + (size_t)(63 - ty) * 262144 + (size_t)(ch0 * 1024) + lane * 16;

        f32x4 acc[4][4] = {};

        // Prologue: stage K-chunk 0 into buffer 0.
        #pragma unroll
        for (int h = 0; h < 2; ++h) {
            async_copy16(baseA + h * 1024, &S[0][0][(ch0 + h) * 512]);
            async_copy16(baseF + h * 1024, &S[0][1][(ch0 + h) * 512]);
        }
        __syncthreads();                         // drains vmcnt (buf0 ready)

        #pragma unroll 4
        for (int step = 0; step < 32; ++step) {
            const int cur = step & 1;
            const int nb = cur ^ 1;
            if (step < 31) {                     // async-stage step+1 into nb
                const size_t off = (size_t)(step + 1) * 8192;
                #pragma unroll
                for (int h = 0; h < 2; ++h) {
                    async_copy16(baseA + off + h * 1024, &S[nb][0][(ch0 + h) * 512]);
                    async_copy16(baseF + off + h * 1024, &S[nb][1][(ch0 + h) * 512]);
                }
            }

            const unsigned short* pa = &S[cur][0][rdA];
            const unsigned short* pf = &S[cur][1][rdF0];
            bf16x8 a[4], b[4];
            #pragma unroll
            for (int fm = 0; fm < 4; ++fm) a[fm] = *(const bf16x8*)(pa + fm * 512);
            #pragma unroll
            for (int fn = 0; fn < 4; ++fn) b[fn] = *(const bf16x8*)(pf + (3 - fn) * 512);
            #pragma unroll
            for (int fm = 0; fm < 4; ++fm)
                #pragma unroll
                for (int fn = 0; fn < 4; ++fn)
                    acc[fm][fn] = __builtin_amdgcn_mfma_f32_16x16x32_bf16(
                        a[fm], b[fn], acc[fm][fn], 0, 0, 0);

            __syncthreads();   // one barrier: completes nb loads, frees cur
        }

        // Epilogue. C/D layout: col = lane&15 (F), row = quad*4+reg (A).
        const float INFV = __uint_as_float(0x7f800000u);
        float sqf[4]; int lf_[4]; bool vf[4];
        #pragma unroll
        for (int fn = 0; fn < 4; ++fn) {
            const int rfl = rowFl0 + wn * 64 + fn * 16 + l15;   // F local
            vf[fn] = rfl < nF;
            const int slotF = 8191 - rfl;       // always in [0,8191]
            sqf[fn] = sqG[slotF];
            lf_[fn] = labG[slotF];
        }
        #pragma unroll
        for (int fm = 0; fm < 4; ++fm) {
            #pragma unroll
            for (int r = 0; r < 4; ++r) {
                const int ra2 = rowA0 + wm * 64 + fm * 16 + quad * 4 + r;
                const bool va = ra2 < nA;
                const int rac = va ? ra2 : 0;
                const float sqa = sqG[rac];
                const int la_ = labG[rac];
                float pmin = INFV, nmin = INFV;
                #pragma unroll
                for (int fn = 0; fn < 4; ++fn) {
                    const float dd = fmaxf(sqa + sqf[fn] - 2.0f * acc[fm][fn][r], 0.0f);
                    if (vf[fn]) {
                        if (la_ == lf_[fn]) pmin = fminf(pmin, dd);
                        else                nmin = fminf(nmin, dd);
                    }
                }
                #pragma unroll
                for (int s = 1; s < 16; s <<= 1) {
                    pmin = fminf(pmin, __shfl_xor(pmin, s));
                    nmin = fminf(nmin, __shfl_xor(nmin, s));
                }
                if (l15 == 0 && va) {
                    if (pmin < INFV) atomicMin(&posmin[ra2], __float_as_uint(pmin));
                    if (nmin < INFV) atomicMin(&negmin[ra2], __float_as_uint(nmin));
                }
            }
        }
        __syncthreads();   // protect LDS before next tile's prologue writes
    }
}

// ---------------------------------------------------------------------------
// Kernel 3: hinge + sum/count with fused finalize via device-scope ticket.
// (R16-validated)
// ---------------------------------------------------------------------------
__global__ __launch_bounds__(256) void reduce_loss(
    const unsigned* __restrict__ posmin, const unsigned* __restrict__ negmin,
    float* __restrict__ accum, unsigned* __restrict__ cnt,
    float* __restrict__ out)
{
    const int i = blockIdx.x * 256 + threadIdx.x;
    const unsigned up = posmin[i], un = negmin[i];
    float tl = 0.0f, c = 0.0f;
    if (up != 0xFFFFFFFFu && un != 0xFFFFFFFFu) {
        const float pd = sqrtf(__uint_as_float(up));
        const float nd = sqrtf(__uint_as_float(un));
        tl = fmaxf(pd - nd + 0.3f, 0.0f);
        c = 1.0f;
    }
    #pragma unroll
    for (int s = 32; s > 0; s >>= 1) {
        tl += __shfl_down(tl, s);
        c  += __shfl_down(c, s);
    }
    __shared__ float sb[8];
    const int lane = threadIdx.x & 63, w = threadIdx.x >> 6;
    if (lane == 0) { sb[w] = tl; sb[4 + w] = c; }
    __syncthreads();
    if (threadIdx.x == 0) {
        atomicAdd(&accum[0], sb[0] + sb[1] + sb[2] + sb[3]);
        atomicAdd(&accum[1], sb[4] + sb[5] + sb[6] + sb[7]);
        __threadfence();
        const unsigned ticket = atomicAdd(&cnt[1], 1u);
        if (ticket == 31u) {               // last of the 32 blocks
            __threadfence();
            const float s2 = atomicAdd(&accum[0], 0.0f);
            const float c2 = atomicAdd(&accum[1], 0.0f);
            out[0] = (c2 > 0.0f) ? s2 / fmaxf(c2, 1.0f) : 0.0f;
        }
    }
}

// ---------------------------------------------------------------------------
extern "C" void kernel_launch(void* const* d_in, const int* in_sizes, int n_in,
                              void* d_out, int out_size, void* d_ws, size_t ws_size,
                              hipStream_t stream) {
    const float* feat  = (const float*)d_in[0];
    const int* labels  = (const int*)d_in[1];
    const int* dom     = (const int*)d_in[2];
    float* out = (float*)d_out;

    char* ws = (char*)d_ws;
    // Workspace layout (bytes) — identical footprint to validated layout.
    // G is now the K-chunk-BLOCKED G2: 64 panels x 256 KiB = 16,777,216 B.
    unsigned short* G   = (unsigned short*)(ws);                 // 16,777,216
    int*      labG      = (int*)(ws + 16777216);                 //     32,768
    float*    sqG       = (float*)(ws + 16809984);               //     32,768
    unsigned* posmin    = (unsigned*)(ws + 16842752);            //     32,768
    unsigned* negmin    = (unsigned*)(ws + 16875520);            //     32,768
    unsigned* cnt       = (unsigned*)(ws + 16908288);            //  8 (nA, ticket)
    float*    accum     = (float*)(ws + 16908296);               //  8 (sum, count)
    // slotOf OVERLAYS posmin: written by compute_slots, consumed and then
    // re-initialized to 0xFF in-place by normalize_rows (same-address order).
    int*      slotOf    = (int*)(ws + 16842752);

    compute_slots<<<1, 256, 0, stream>>>(dom, slotOf, cnt, accum);
    normalize_rows<<<B_ROWS / 4, 256, 0, stream>>>(feat, labels, slotOf,
                                                   negmin, G, labG, sqG);

    // Grid 1056 = 8 XCD groups x 132; per-XCD rectangle mapping in-kernel.
    tile_mindist<<<1056, 256, 0, stream>>>(G, labG, sqG, cnt, posmin, negmin);

    reduce_loss<<<B_ROWS / 256, 256, 0, stream>>>(posmin, negmin, accum, cnt, out);
}